// Round 17
// baseline (347.282 us; speedup 1.0000x reference)
//
// FCGPFA variational iteration for MI355X (gfx950). Round 17: k_sys2's LDS
// instruction count cut ~4x: (a) Newton-Schulz on ONE wave, 4x4 register
// tiles, float4 reads both operands via symmetry of M and all NS iterates
// (2 LDS instr / 16 MAC, zero barriers -- in-order DS pipe, proven pattern);
// (b) Mhat-build 4x4-tile float4 (r13 partial-reduce); (c) P10 as tiled
// Z=CP GEMM with fused q_t (r15 k_fin pattern inlined); (d) Q in LDS.
// LDW/CL -> 36 (16B alignment). All other kernels identical to round 16.
//
#include <hip/hip_runtime.h>
#include <math.h>

namespace {
constexpr int Mb   = 16;
constexpr int Nn   = 96;
constexpr int NTF  = 350;
constexpr int Tt   = 300;
constexpr int NSUB = 8;
constexpr int NTAU = 20;
constexpr int NL   = 8;
constexpr int ML   = Mb * NL;   // 128 systems
constexpr int R_   = 32;        // low-rank dimension
constexpr int CS   = 33;        // C global row stride
constexpr int CL   = 36;        // C LDS row stride (x4 -> float4-aligned)
constexpr int LDW  = 36;        // P/M row stride (float4-aligned)
constexpr int TP   = 320;
constexpr int CROWS= 384;
constexpr int NSIT = 12;        // Newton-Schulz iterations (even!)
constexpr float EPS = 0.001f;
}

__device__ __forceinline__ int PIV(int k) { return (600 * k + 300) >> 6; }

__device__ __forceinline__ float  sqrt_(float x)  { return sqrtf(x); }
__device__ __forceinline__ double sqrt_(double x) { return sqrt(x); }

__device__ __forceinline__ void lfence() {
  asm volatile("s_waitcnt lgkmcnt(0)" ::: "memory");
}

// ------------- 32x32 Cholesky (lower) + W = L^-1 (setup only, proven r14) ---
template <typename T>
__device__ void chol32_trtri32(T* A, T* W, T* rd, T* V, int tid) {
  if (tid < 32) {
    const int r = tid;
    for (int c = 0; c < 32; ++c) {
      T dotp = (T)0, dotv = (T)0;
      for (int k = 0; k < c; ++k) {
        const T bc = A[c * LDW + k];
        dotp += bc * bc;
        dotv += A[r * LDW + k] * bc;
      }
      const T pivot = A[c * LDW + c] - dotp;
      T s, is;
      if (pivot > (T)1e-12) { s = sqrt_(pivot); is = (T)1 / s; }
      else                  { s = (T)0;         is = (T)0; }
      if (r == c)      { A[c * LDW + c] = s; rd[c] = is; }
      else if (r > c)  A[r * LDW + c] = (A[r * LDW + c] - dotv) * is;
      lfence();
    }
  }
  __syncthreads();
  if (tid < 32) {
    const int c = tid;
    V[c * LDW + c] = rd[c];
    for (int r = c + 1; r < 32; ++r) {
      T acc = (T)0;
      for (int k = c; k < r; ++k) acc += A[r * LDW + k] * V[k * LDW + c];
      V[r * LDW + c] = -acc * rd[r];
    }
    for (int r = 0; r < 32; ++r)
      W[r * LDW + c] = (r < c) ? (T)0 : V[r * LDW + c];
  }
  __syncthreads();
}

// ---------------------------------------------------------------- S1: weights
__global__ __launch_bounds__(256) void k_weights(
    const float* __restrict__ Yraw, const float* __restrict__ kern,
    const float* __restrict__ wproj, float* __restrict__ WA,
    float* __restrict__ Yt) {
  __shared__ float sk[NTAU * NSUB];
  __shared__ float sp[NSUB * NL];
  const int tid = threadIdx.x;
  if (tid < NTAU * NSUB) sk[tid] = kern[tid];
  if (tid < NSUB * NL)   sp[tid] = wproj[tid];
  __syncthreads();
  const int g = blockIdx.x * 256 + tid;            // g = (m*Tt + t)*Nn + n
  if (g >= Mb * Tt * Nn) return;
  const int n  = g % Nn;
  const int mt = g / Nn;
  const int t  = mt % Tt;
  const int m  = mt / Tt;
  const float* yr = Yraw + ((size_t)m * Nn + n) * NTF + 30 + t;
  float ya[NTAU + 1];
#pragma unroll
  for (int j = 0; j <= NTAU; ++j) ya[j] = yr[j];
  float gs[NSUB];
#pragma unroll
  for (int s = 0; s < NSUB; ++s) {
    float acc = 0.f;
#pragma unroll
    for (int j = 0; j < NTAU; ++j) acc += ya[j] * sk[(NTAU - 1 - j) * NSUB + s];
    gs[s] = (fabsf(acc) < 1e-5f) ? 0.f : acc;      // reference threshold
  }
  float w[NL];
#pragma unroll
  for (int l = 0; l < NL; ++l) {
    float acc = 0.f;
#pragma unroll
    for (int s = 0; s < NSUB; ++s) acc += gs[s] * sp[s * NL + l];
    w[l] = acc;
  }
  float4* wa4 = reinterpret_cast<float4*>(WA + (size_t)g * NL);
  wa4[0] = make_float4(w[0], w[1], w[2], w[3]);
  wa4[1] = make_float4(w[4], w[5], w[6], w[7]);
  Yt[g] = ya[NTAU];
}

// ---- S2a: M = K[S,S] (fp64) -> chol32+trtri32 -> W_S (global) --------------
__global__ __launch_bounds__(256) void k_scholM(
    const float* __restrict__ K, double* __restrict__ WS64) {
  __shared__ double A[R_ * LDW];
  __shared__ double V[R_ * LDW];
  __shared__ double rd[R_];
  const int tid = threadIdx.x;
  for (int e = tid; e < R_ * R_; e += 256) {
    const int a = e >> 5, b = e & 31;
    A[a * LDW + b] = (double)K[(size_t)PIV(a) * Tt + PIV(b)];
  }
  __syncthreads();
  chol32_trtri32<double>(A, WS64, rd, V, tid);
}

// ---- S2b: C[t][k] = sum_{j<=k} W_S[k][j]*K[p_j][t]; k==R_ zeroes pad col ---
__global__ __launch_bounds__(320) void k_cmake(
    const float* __restrict__ K, const double* __restrict__ WS64,
    float* __restrict__ Cg) {
  const int k = blockIdx.x;            // 0..32
  const int t = threadIdx.x;
  if (k == R_) {
    for (int r = t; r < CROWS; r += 320) Cg[(size_t)r * CS + R_] = 0.f;
    return;
  }
  __shared__ double wrow[R_];
  if (t < R_) wrow[t] = WS64[(size_t)k * LDW + t];
  __syncthreads();
  if (t < Tt) {
    double acc = 0.0;
    for (int j = 0; j <= k; ++j)
      acc += wrow[j] * (double)K[(size_t)PIV(j) * Tt + t];
    Cg[(size_t)t * CS + k] = (float)acc;
  }
  for (int r = Tt + t; r < CROWS; r += 320) Cg[(size_t)r * CS + k] = 0.f;
}

// ---------------- S3a: R64 = eps*I + C^T C (fp64, 4 WGs) --------------------
__global__ __launch_bounds__(256) void k_rmul(
    const float* __restrict__ Cg, double* __restrict__ R64) {
  const int e = blockIdx.x * 256 + threadIdx.x;
  if (e >= R_ * R_) return;
  const int i = e >> 5, j = e & 31;
  double acc = (i == j) ? 0.001 : 0.0;
  for (int r = 0; r < Tt; ++r)
    acc += (double)Cg[(size_t)r * CS + i] * (double)Cg[(size_t)r * CS + j];
  R64[e] = acc;
}

// --------------- S3b: chol32+trtri32 of R (fp64), W -> global ---------------
__global__ __launch_bounds__(256) void k_qchol(
    const double* __restrict__ R64, double* __restrict__ W64) {
  __shared__ double A[R_ * LDW];
  __shared__ double V[R_ * LDW];
  __shared__ double rd[R_];
  const int tid = threadIdx.x;
  for (int e = tid; e < R_ * R_; e += 256) {
    const int i = e >> 5, j = e & 31;
    A[i * LDW + j] = R64[e];
  }
  __syncthreads();
  chol32_trtri32<double>(A, W64, rd, V, tid);
}

// --------------- S3c: Q64 = W^T W (fp64, 4 WGs) -----------------------------
__global__ __launch_bounds__(256) void k_qmul(
    const double* __restrict__ W64, double* __restrict__ Qg) {
  const int e = blockIdx.x * 256 + threadIdx.x;
  if (e >= R_ * R_) return;
  const int i = e >> 5, j = e & 31;
  const int k0 = (i > j) ? i : j;
  double acc = 0.0;
  for (int k = k0; k < R_; ++k) acc += W64[k * LDW + i] * W64[k * LDW + j];
  Qg[e] = acc;
}

// ------------------------------- S4: init (dh0 = 1 + eps) -------------------
__global__ __launch_bounds__(256) void k_init(
    float* __restrict__ mu, float* __restrict__ dh) {
  const int g = blockIdx.x * 256 + threadIdx.x;
  if (g >= Mb * Tt * NL) return;
  mu[g] = 0.f;
  dh[g] = 1.0f + EPS;
}

// ---- I1: fused lambda + gradient (proven r16) ------------------------------
__global__ __launch_bounds__(256) void k_gd2(
    const float* __restrict__ WA, const float* __restrict__ Yt,
    const float* __restrict__ mug, const float* __restrict__ dhg,
    const float* __restrict__ biasp, float* __restrict__ g1,
    float* __restrict__ dvec) {
  const int wg = blockIdx.x;           // 0..159
  const int m = wg / 10, ch = wg - m * 10;
  const int t0 = ch * 30;
  const int tid = threadIdx.x;
  __shared__ float pg[30 * 8 * 8];     // [tl][l][nq]
  __shared__ float pd[30 * 8 * 8];
  if (tid < 240) {
    const int tl = tid >> 3, nq = tid & 7;
    const int t = t0 + tl;
    const float b = biasp[0];
    const float4* mp = reinterpret_cast<const float4*>(mug + ((size_t)m * Tt + t) * NL);
    const float4* dp = reinterpret_cast<const float4*>(dhg + ((size_t)m * Tt + t) * NL);
    const float4 m0 = mp[0], m1 = mp[1], h0 = dp[0], h1 = dp[1];
    const float mv[8] = {m0.x, m0.y, m0.z, m0.w, m1.x, m1.y, m1.z, m1.w};
    const float hv[8] = {0.5f * h0.x, 0.5f * h0.y, 0.5f * h0.z, 0.5f * h0.w,
                         0.5f * h1.x, 0.5f * h1.y, 0.5f * h1.z, 0.5f * h1.w};
    float ga[8], dd[8];
#pragma unroll
    for (int l = 0; l < 8; ++l) { ga[l] = 0.f; dd[l] = 0.f; }
    const float* war = WA + ((size_t)m * Tt + t) * Nn * NL;
    const float* ytr = Yt + ((size_t)m * Tt + t) * Nn;
    for (int i = 0; i < 12; ++i) {
      const int n = nq + 8 * i;
      const float4* w4 = reinterpret_cast<const float4*>(war + n * NL);
      const float4 w0 = w4[0], w1 = w4[1];
      const float wv[8] = {w0.x, w0.y, w0.z, w0.w, w1.x, w1.y, w1.z, w1.w};
      float e = b;
#pragma unroll
      for (int l = 0; l < 8; ++l) e += wv[l] * (mv[l] + wv[l] * hv[l]);
      const float lamn = expf(e);
      const float dy = ytr[n] - lamn;
#pragma unroll
      for (int l = 0; l < 8; ++l) {
        ga[l] += wv[l] * dy;
        dd[l] += wv[l] * wv[l] * lamn;
      }
    }
#pragma unroll
    for (int l = 0; l < 8; ++l) {
      pg[(tl * 8 + l) * 8 + nq] = ga[l];
      pd[(tl * 8 + l) * 8 + nq] = dd[l];
    }
  }
  __syncthreads();
  if (tid < 240) {
    const int tl = tid >> 3, l = tid & 7;
    float sg_ = 0.f, sd_ = 0.f;
#pragma unroll
    for (int nq = 0; nq < 8; ++nq) {
      sg_ += pg[(tl * 8 + l) * 8 + nq];
      sd_ += pd[(tl * 8 + l) * 8 + nq];
    }
    const size_t idx = (size_t)(m * NL + l) * TP + (t0 + tl);
    g1[idx]   = sg_;
    dvec[idx] = sd_;
  }
}

// ---- I2: fused per-system solve (LDS-instruction-optimized) ----------------
__global__ __launch_bounds__(320) void k_sys2(
    const float* __restrict__ Cg, const double* __restrict__ Qg,
    const float* __restrict__ g1, const float* __restrict__ dvec,
    float* __restrict__ mug, float* __restrict__ dhg) {
  const int ml = blockIdx.x;
  const int mt = ml / NL, lat = ml % NL;
  const int tid = threadIdx.x;                     // 0..319
  __shared__ float  Cf[Tt * CL];                   // 43.2 KB
  __shared__ float  M[R_ * LDW];                   // 4.6 KB
  __shared__ float  Xa[R_ * LDW];
  __shared__ float  Xb[R_ * LDW];
  __shared__ float  T[R_ * LDW];                   // 13.8 KB
  __shared__ float  scratch[4096];                 // 16 KB: part (P6) / redq (P10)
  __shared__ float  muv[Tt], gv[Tt], sv[Tt], dl[Tt], sg[Tt];
  __shared__ double Qs[R_ * R_];                   // 8 KB
  __shared__ double pv[R_], qv[R_];
  __shared__ double pB[R_ * 10];
  __shared__ float  pU[R_ * 10];
  __shared__ float  uv[R_], yv[R_];
  __shared__ float  redg[R_ + 2];
  // P1: stage C, Q, vectors
  for (int e = tid; e < Tt * CS; e += 320) {
    const int r = e / CS, c = e - r * CS;
    Cf[r * CL + c] = Cg[e];
  }
  for (int e = tid; e < R_ * R_; e += 320) Qs[e] = Qg[e];
  if (tid < Tt) {
    const float m_ = mug[((size_t)mt * Tt + tid) * NL + lat];
    const float g_ = g1[(size_t)ml * TP + tid];
    const float d_ = dvec[(size_t)ml * TP + tid];
    muv[tid] = m_; gv[tid] = g_;
    const float s = 1.f / (1.f + EPS * d_);
    sv[tid] = s;
    dl[tid] = d_ * s;
  }
  __syncthreads();
  // P2: p = C^T mu (fp64) -- 32 cols x 10 chunks of 30 rows
  {
    const int k = tid & 31, ch = tid >> 5;
    double acc = 0.0;
    const int ta = ch * 30;
    for (int t = ta; t < ta + 30; ++t)
      acc += (double)Cf[t * CL + k] * (double)muv[t];
    pB[k * 10 + ch] = acc;
  }
  __syncthreads();
  if (tid < R_) {
    double a = 0.0;
    for (int ch = 0; ch < 10; ++ch) a += pB[tid * 10 + ch];
    pv[tid] = a;
  }
  __syncthreads();
  // P3: q = Q p (fp64, Q in LDS)
  if (tid < R_) {
    double acc = 0.0;
    for (int j = 0; j < R_; ++j) acc += Qs[j * R_ + tid] * pv[j];
    qv[tid] = acc;
  }
  __syncthreads();
  // P4: grad = g1 - 1000*(mu - C q) [fp64 inner]
  if (tid < Tt) {
    double cq = 0.0;
    for (int k = 0; k < R_; ++k) cq += (double)Cf[tid * CL + k] * qv[k];
    const double gnew = (double)gv[tid] - 1000.0 * ((double)muv[tid] - cq);
    gv[tid] = (float)gnew;
    sg[tid] = sv[tid] * (float)gnew;
  }
  __syncthreads();
  // P5: u = C^T (s*grad)
  {
    const int k = tid & 31, ch = tid >> 5;
    float acc = 0.f;
    const int ta = ch * 30;
    for (int t = ta; t < ta + 30; ++t) acc += Cf[t * CL + k] * sg[t];
    pU[k * 10 + ch] = acc;
  }
  __syncthreads();
  if (tid < R_) {
    float a = 0.f;
    for (int ch = 0; ch < 10; ++ch) a += pU[tid * 10 + ch];
    uv[tid] = a;
  }
  // P6: Mhat partials -- 4x4 tiles x 4 k-chunks (75 t each), float4 reads
  if (tid < 256) {
    const int ch = tid >> 6, til = tid & 63;
    const int i0 = (til >> 3) * 4, j0 = (til & 7) * 4;
    float acc[4][4];
#pragma unroll
    for (int r = 0; r < 4; ++r)
#pragma unroll
      for (int c = 0; c < 4; ++c) acc[r][c] = 0.f;
    const int ta = ch * 75, tb = ta + 75;
    for (int t = ta; t < tb; ++t) {
      const float w = dl[t];
      const float4 u = *reinterpret_cast<const float4*>(&Cf[t * CL + i0]);
      const float4 v = *reinterpret_cast<const float4*>(&Cf[t * CL + j0]);
      const float ua[4] = {u.x * w, u.y * w, u.z * w, u.w * w};
      const float vb[4] = {v.x, v.y, v.z, v.w};
#pragma unroll
      for (int r = 0; r < 4; ++r)
#pragma unroll
        for (int c = 0; c < 4; ++c) acc[r][c] += ua[r] * vb[c];
    }
    float* p = &scratch[(ch * 64 + til) * 16];
#pragma unroll
    for (int r = 0; r < 4; ++r)
#pragma unroll
      for (int c = 0; c < 4; ++c) p[r * 4 + c] = acc[r][c];
  }
  __syncthreads();
  // reduce 4 chunks -> M (+I)
  for (int e = tid; e < R_ * R_; e += 320) {
    const int i = e >> 5, j = e & 31;
    const int til = (i >> 2) * 8 + (j >> 2);
    const int el = (i & 3) * 4 + (j & 3);
    const float val = scratch[(0 * 64 + til) * 16 + el] + scratch[(1 * 64 + til) * 16 + el]
                    + scratch[(2 * 64 + til) * 16 + el] + scratch[(3 * 64 + til) * 16 + el];
    M[i * LDW + j] = val + ((i == j) ? 1.f : 0.f);
  }
  __syncthreads();
  // P7: Gershgorin bound, X0 = I/G
  if (tid < R_) {
    float rs = 0.f;
    for (int j = 0; j < R_; ++j) rs += fabsf(M[tid * LDW + j]);
    redg[tid] = rs;
  }
  __syncthreads();
  if (tid == 0) {
    float g = 0.f;
    for (int i = 0; i < R_; ++i) g = fmaxf(g, redg[i]);
    redg[R_] = 1.f / g;
  }
  __syncthreads();
  {
    const float c0 = redg[R_];
    for (int e = tid; e < R_ * R_; e += 320) {
      const int i = e >> 5, j = e & 31;
      Xa[i * LDW + j] = (i == j) ? c0 : 0.f;
    }
  }
  __syncthreads();
  // P8: Newton-Schulz on WAVE 0 only -- 4x4 tiles, float4 both operands via
  // symmetry of M and iterates; zero barriers (in-order DS pipe + lfence).
  if (tid < 64) {
    const int i0 = (tid >> 3) * 4, j0 = (tid & 7) * 4;
    float* Xc = Xa;
    float* Xn = Xb;
    for (int it = 0; it < NSIT; ++it) {
      // T = M Xc:  T[i0+r][j0+c] = sum_k M[k][i0+r] * Xc[k][j0+c]  (M sym)
      {
        float acc[4][4];
#pragma unroll
        for (int r = 0; r < 4; ++r)
#pragma unroll
          for (int c = 0; c < 4; ++c) acc[r][c] = 0.f;
        for (int k = 0; k < R_; ++k) {
          const float4 m4 = *reinterpret_cast<const float4*>(&M[k * LDW + i0]);
          const float4 x4 = *reinterpret_cast<const float4*>(&Xc[k * LDW + j0]);
          const float ma[4] = {m4.x, m4.y, m4.z, m4.w};
          const float xb4[4] = {x4.x, x4.y, x4.z, x4.w};
#pragma unroll
          for (int r = 0; r < 4; ++r)
#pragma unroll
            for (int c = 0; c < 4; ++c) acc[r][c] += ma[r] * xb4[c];
        }
#pragma unroll
        for (int r = 0; r < 4; ++r)
          *reinterpret_cast<float4*>(&T[(i0 + r) * LDW + j0]) =
              make_float4(acc[r][0], acc[r][1], acc[r][2], acc[r][3]);
      }
      lfence();
      // Xn = 2 Xc - Xc T:  uses Xc[k][i0:4] (sym) and T[k][j0:4]
      {
        float acc[4][4];
#pragma unroll
        for (int r = 0; r < 4; ++r)
#pragma unroll
          for (int c = 0; c < 4; ++c) acc[r][c] = 0.f;
        for (int k = 0; k < R_; ++k) {
          const float4 x4 = *reinterpret_cast<const float4*>(&Xc[k * LDW + i0]);
          const float4 t4 = *reinterpret_cast<const float4*>(&T[k * LDW + j0]);
          const float xa4[4] = {x4.x, x4.y, x4.z, x4.w};
          const float tb4[4] = {t4.x, t4.y, t4.z, t4.w};
#pragma unroll
          for (int r = 0; r < 4; ++r)
#pragma unroll
            for (int c = 0; c < 4; ++c) acc[r][c] += xa4[r] * tb4[c];
        }
#pragma unroll
        for (int r = 0; r < 4; ++r) {
          const float4 xc4 = *reinterpret_cast<const float4*>(&Xc[(i0 + r) * LDW + j0]);
          *reinterpret_cast<float4*>(&Xn[(i0 + r) * LDW + j0]) =
              make_float4(2.f * xc4.x - acc[r][0], 2.f * xc4.y - acc[r][1],
                          2.f * xc4.z - acc[r][2], 2.f * xc4.w - acc[r][3]);
        }
      }
      lfence();
      float* tmp = Xc; Xc = Xn; Xn = tmp;
    }
  }
  __syncthreads();                     // NSIT even -> P = Xa
  // P9: y = P u
  if (tid < R_) {
    float acc = 0.f;
    for (int j = 0; j < R_; ++j) acc += Xa[tid * LDW + j] * uv[j];
    yv[tid] = acc;
  }
  __syncthreads();
  // P10: Z = C P tiles (4t x 4i), fused q-partials -> redq[t][8]
  float* redq = scratch;               // 2400 floats
  for (int tix = tid; tix < 600; tix += 320) {
    const int ig = tix & 7, tg = tix >> 3;
    const int t0 = tg * 4, i0 = ig * 4;
    float acc[4][4];
#pragma unroll
    for (int r = 0; r < 4; ++r)
#pragma unroll
      for (int c = 0; c < 4; ++c) acc[r][c] = 0.f;
    for (int k = 0; k < R_; ++k) {
      const float4 p4 = *reinterpret_cast<const float4*>(&Xa[k * LDW + i0]);
      const float pa[4] = {p4.x, p4.y, p4.z, p4.w};
      const float cr0 = Cf[(t0 + 0) * CL + k];
      const float cr1 = Cf[(t0 + 1) * CL + k];
      const float cr2 = Cf[(t0 + 2) * CL + k];
      const float cr3 = Cf[(t0 + 3) * CL + k];
#pragma unroll
      for (int c = 0; c < 4; ++c) {
        acc[0][c] += cr0 * pa[c];
        acc[1][c] += cr1 * pa[c];
        acc[2][c] += cr2 * pa[c];
        acc[3][c] += cr3 * pa[c];
      }
    }
#pragma unroll
    for (int r = 0; r < 4; ++r) {
      const float4 c4 = *reinterpret_cast<const float4*>(&Cf[(t0 + r) * CL + i0]);
      const float qp = acc[r][0] * c4.x + acc[r][1] * c4.y
                     + acc[r][2] * c4.z + acc[r][3] * c4.w;
      redq[(t0 + r) * 8 + ig] = qp;
    }
  }
  __syncthreads();
  // P11: outputs
  if (tid < Tt) {
    float q = 0.f;
#pragma unroll
    for (int g = 0; g < 8; ++g) q += redq[tid * 8 + g];
    float cy = 0.f;
    for (int k = 0; k < R_; ++k) cy += Cf[tid * CL + k] * yv[k];
    const float s = sv[tid];
    const size_t idx = ((size_t)mt * Tt + tid) * NL + lat;
    const float x2 = EPS * s * gv[tid] + s * cy;
    mug[idx] = muv[tid] + 0.5f * x2;                // LR = 0.5
    dhg[idx] = -(EPS * s + s * s * q);
  }
}

// ---------------------------------------------------------------- F1: output
__global__ __launch_bounds__(256) void k_out(
    const float* __restrict__ mu, float* __restrict__ out) {
  const int g = blockIdx.x * 256 + threadIdx.x;   // g = (m*NL + l)*Tt + t
  if (g >= Mb * NL * Tt) return;
  const int t = g % Tt;
  const int ml = g / Tt;
  const int m = ml / NL, l = ml % NL;
  out[g] = mu[((size_t)m * Tt + t) * NL + l];
}

// ------------------------------------------------------------------- launcher
extern "C" void kernel_launch(void* const* d_in, const int* in_sizes, int n_in,
                              void* d_out, int out_size, void* d_ws, size_t ws_size,
                              hipStream_t stream) {
  (void)in_sizes; (void)n_in; (void)out_size;
  const float* Yraw  = (const float*)d_in[0];
  const float* kern  = (const float*)d_in[1];
  const float* wproj = (const float*)d_in[2];
  const float* K     = (const float*)d_in[3];
  const float* biasp = (const float*)d_in[4];
  float* out = (float*)d_out;

  char* base = (char*)d_ws;
  size_t off = 0;
  auto alloc = [&](size_t bytes) -> void* {
    void* p = base + off;
    off += (bytes + 511) & ~(size_t)511;
    return p;
  };
  float*  WA   = (float*) alloc((size_t)Mb * Tt * Nn * NL * 4);
  float*  Yt   = (float*) alloc((size_t)Mb * Tt * Nn * 4);
  float*  mu   = (float*) alloc((size_t)Mb * Tt * NL * 4);
  float*  dh   = (float*) alloc((size_t)Mb * Tt * NL * 4);
  float*  g1   = (float*) alloc((size_t)ML * TP * 4);
  float*  dvec = (float*) alloc((size_t)ML * TP * 4);
  float*  Cg   = (float*) alloc((size_t)CROWS * CS * 4);
  double* WS64 = (double*)alloc((size_t)R_ * LDW * 8);
  double* W64  = (double*)alloc((size_t)R_ * LDW * 8);
  double* R64  = (double*)alloc((size_t)R_ * R_ * 8);
  double* Q64  = (double*)alloc((size_t)R_ * R_ * 8);
  if (off > ws_size) return;

  const int gMTN = (Mb * Tt * Nn) / 256;       // 1800
  const int gMTL = (Mb * Tt * NL + 255) / 256; // 150
  const int gRR  = (R_ * R_ + 255) / 256;      // 4

  k_weights<<<gMTN, 256, 0, stream>>>(Yraw, kern, wproj, WA, Yt);
  k_scholM<<<1, 256, 0, stream>>>(K, WS64);
  k_cmake<<<R_ + 1, 320, 0, stream>>>(K, WS64, Cg);
  k_rmul<<<gRR, 256, 0, stream>>>(Cg, R64);
  k_qchol<<<1, 256, 0, stream>>>(R64, W64);
  k_qmul<<<gRR, 256, 0, stream>>>(W64, Q64);
  k_init<<<gMTL, 256, 0, stream>>>(mu, dh);

  for (int it = 0; it < 5; ++it) {
    k_gd2<<<Mb * 10, 256, 0, stream>>>(WA, Yt, mu, dh, biasp, g1, dvec);
    k_sys2<<<ML, 320, 0, stream>>>(Cg, Q64, g1, dvec, mu, dh);
  }
  k_out<<<gMTL, 256, 0, stream>>>(mu, out);
}